// Round 1
// baseline (1347.828 us; speedup 1.0000x reference)
//
#include <hip/hip_runtime.h>

// RaggedGravNet_simple on MI355X.
// Pipeline: k_transform (coords+feat GEMMs) -> k_knn (39-NN per 4096-segment)
//           -> k_gather<64> -> k_dense<192> -> k_gather<128> -> k_dense<320> -> out
// All fp32. kNN uses s = cn_j - 2*q.c_j (rank-equivalent to d2) with a
// per-lane LDS FIFO + batched drains into a sorted top-39 list to avoid
// wave-divergent insertion cost in the inner loop.

#define NPTS 32768
#define SEGSZ 4096
#define KN 39
#define FIFO_CAP 96

// ---------------------------------------------------------------- transform
__global__ __launch_bounds__(128) void k_transform(
    const float* __restrict__ x,
    const float* __restrict__ Ws, const float* __restrict__ bs,
    const float* __restrict__ Wf, const float* __restrict__ bf,
    float4* __restrict__ coords, float* __restrict__ feat) {
  __shared__ float sWf[64 * 64];
  __shared__ float sWs[64 * 4];
  __shared__ float sb[68];
  __shared__ float sx[128 * 65];
  const int t = threadIdx.x;
  for (int i = t; i < 4096; i += 128) sWf[i] = Wf[i];
  for (int i = t; i < 256; i += 128) sWs[i] = Ws[i];
  if (t < 64) sb[t] = bf[t];
  else if (t < 68) sb[t] = bs[t - 64];
  const int rowbase = blockIdx.x * 128;
  for (int i = t; i < 128 * 64; i += 128) {
    int r = i >> 6, k = i & 63;
    sx[r * 65 + k] = x[(size_t)rowbase * 64 + i];
  }
  __syncthreads();
  const float* xr = sx + t * 65;
  float c0 = sb[64], c1 = sb[65], c2 = sb[66], c3 = sb[67];
  for (int k = 0; k < 64; k++) {
    float xs = xr[k];
    c0 = fmaf(xs, sWs[k * 4 + 0], c0);
    c1 = fmaf(xs, sWs[k * 4 + 1], c1);
    c2 = fmaf(xs, sWs[k * 4 + 2], c2);
    c3 = fmaf(xs, sWs[k * 4 + 3], c3);
  }
  const int row = rowbase + t;
  coords[row] = make_float4(c0, c1, c2, c3);
  for (int fc = 0; fc < 64; fc += 16) {
    float acc[16];
#pragma unroll
    for (int j = 0; j < 16; j++) acc[j] = sb[fc + j];
    for (int k = 0; k < 64; k++) {
      float xs = xr[k];
#pragma unroll
      for (int j = 0; j < 16; j++) acc[j] = fmaf(xs, sWf[k * 64 + fc + j], acc[j]);
    }
#pragma unroll
    for (int j = 0; j < 16; j += 4)
      *(float4*)(feat + (size_t)row * 64 + fc + j) =
          make_float4(acc[j], acc[j + 1], acc[j + 2], acc[j + 3]);
  }
}

// ---------------------------------------------------------------- kNN
__global__ __launch_bounds__(128) void k_knn(
    const float4* __restrict__ coords, int* __restrict__ nidx,
    float* __restrict__ wout) {
  __shared__ float4 cc[1024];
  __shared__ float scn[1024];
  __shared__ float ld[KN * 128];
  __shared__ unsigned short li[KN * 128];
  __shared__ unsigned short fifo[FIFO_CAP * 128];
  const int t = threadIdx.x;
  const int q = blockIdx.x * 128 + t;
  const int seg = q >> 12;
  const int segbase = seg << 12;
  const int qlocal = q - segbase;
  const float4 qc = coords[q];
  const float cnq = qc.x * qc.x + qc.y * qc.y + qc.z * qc.z + qc.w * qc.w;

#pragma unroll 4
  for (int j = 0; j < KN; j++) ld[j * 128 + t] = 1e30f;
  float worst = 1e30f;
  int fn = 0;

  auto drain = [&](int cb) {
    for (int i = 0; i < fn; i++) {
      int lj = fifo[i * 128 + t];
      float4 c = cc[lj];
      float dotv = qc.x * c.x + qc.y * c.y + qc.z * c.z + qc.w * c.w;
      float s = fmaf(-2.0f, dotv, scn[lj]);
      if (s < worst) {
        int p = KN - 1;
        while (p > 0 && ld[(p - 1) * 128 + t] > s) {
          ld[p * 128 + t] = ld[(p - 1) * 128 + t];
          li[p * 128 + t] = li[(p - 1) * 128 + t];
          p--;
        }
        ld[p * 128 + t] = s;
        li[p * 128 + t] = (unsigned short)(cb + lj);
        worst = ld[(KN - 1) * 128 + t];
      }
    }
    fn = 0;
  };

  for (int cb = 0; cb < SEGSZ; cb += 1024) {
    __syncthreads();
#pragma unroll
    for (int u = 0; u < 8; u++) {
      float4 c = coords[segbase + cb + u * 128 + t];
      cc[u * 128 + t] = c;
      scn[u * 128 + t] = c.x * c.x + c.y * c.y + c.z * c.z + c.w * c.w;
    }
    __syncthreads();
    const int selfj = qlocal - cb;
    int start = 0;
    while (start < 1024) {
      int end = 1024;
      if (cb == 0) end = (start == 0) ? 64 : ((start * 2 < 1024) ? start * 2 : 1024);
      for (int j = start; j < end; j++) {
        float4 c = cc[j];
        float dotv = qc.x * c.x + qc.y * c.y + qc.z * c.z + qc.w * c.w;
        float s = fmaf(-2.0f, dotv, scn[j]);
        if (s < worst && j != selfj) {
          if (fn == FIFO_CAP) drain(cb);  // safety valve (astronomically rare)
          fifo[fn * 128 + t] = (unsigned short)j;
          fn++;
        }
      }
      drain(cb);
      start = end;
    }
  }
  for (int jj = 0; jj < KN; jj++) {
    float s = ld[jj * 128 + t];
    int gl = segbase + (int)li[jj * 128 + t];
    nidx[(size_t)q * KN + jj] = gl;
    float d2 = s + cnq;
    wout[(size_t)q * KN + jj] = expf(-(d2 * 10.0f + 1e-5f));
  }
}

// ---------------------------------------------------------------- gather/agg
template <int F>
__global__ __launch_bounds__(256) void k_gather(
    const float* __restrict__ feat, const int* __restrict__ nidx,
    const float* __restrict__ w, float* __restrict__ agg) {
  constexpr int TPR = F / 16;
  const int gid = blockIdx.x * 256 + threadIdx.x;
  const int row = gid / TPR;
  const int fb = (gid % TPR) * 16;
  float mx[16], sm[16];
#pragma unroll
  for (int j = 0; j < 16; j++) { mx[j] = -1e30f; sm[j] = 0.0f; }
  const int* ni = nidx + (size_t)row * KN;
  const float* wr = w + (size_t)row * KN;
  for (int k = 0; k < KN; k++) {
    int n = ni[k];
    float wv = wr[k];
    const float4* fp = (const float4*)(feat + (size_t)n * F + fb);
#pragma unroll
    for (int v = 0; v < 4; v++) {
      float4 f4 = fp[v];
      float a;
      a = f4.x * wv; mx[4 * v + 0] = fmaxf(mx[4 * v + 0], a); sm[4 * v + 0] += a;
      a = f4.y * wv; mx[4 * v + 1] = fmaxf(mx[4 * v + 1], a); sm[4 * v + 1] += a;
      a = f4.z * wv; mx[4 * v + 2] = fmaxf(mx[4 * v + 2], a); sm[4 * v + 2] += a;
      a = f4.w * wv; mx[4 * v + 3] = fmaxf(mx[4 * v + 3], a); sm[4 * v + 3] += a;
    }
  }
  const float inv = 1.0f / (float)KN;
  float* am = agg + (size_t)row * (2 * F) + fb;
#pragma unroll
  for (int v = 0; v < 4; v++)
    ((float4*)am)[v] = make_float4(mx[4 * v], mx[4 * v + 1], mx[4 * v + 2], mx[4 * v + 3]);
  float* as = am + F;
#pragma unroll
  for (int v = 0; v < 4; v++)
    ((float4*)as)[v] = make_float4(sm[4 * v] * inv, sm[4 * v + 1] * inv,
                                   sm[4 * v + 2] * inv, sm[4 * v + 3] * inv);
}

// ---------------------------------------------------------------- dense+tanh
template <int KDIM>
__global__ __launch_bounds__(256) void k_dense(
    const float* __restrict__ x, const float* __restrict__ agg,
    const float* __restrict__ W, const float* __restrict__ b,
    float* __restrict__ out) {
  __shared__ __align__(16) float sW[64 * 128];
  __shared__ __align__(16) float sIn[64 * 64];
  const int t = threadIdx.x;
  const int rowbase = blockIdx.x * 64;
  const int cg = (t & 31) * 4;
  const int rg = (t >> 5) * 8;
  constexpr int ASTRIDE = KDIM - 64;
  float acc[8][4];
  float4 bv = *(const float4*)(b + cg);
#pragma unroll
  for (int r = 0; r < 8; r++) {
    acc[r][0] = bv.x; acc[r][1] = bv.y; acc[r][2] = bv.z; acc[r][3] = bv.w;
  }
  for (int kt = 0; kt < KDIM; kt += 64) {
    __syncthreads();
#pragma unroll
    for (int i = 0; i < 8; i++) {
      int idx = t + i * 256;
      ((float4*)sW)[idx] = ((const float4*)(W + (size_t)kt * 128))[idx];
    }
    const float* src = (kt == 0) ? (x + (size_t)rowbase * 64)
                                 : (agg + (size_t)rowbase * ASTRIDE + (kt - 64));
    const int stride = (kt == 0) ? 64 : ASTRIDE;
#pragma unroll
    for (int i = 0; i < 4; i++) {
      int idx = t + i * 256;
      int r = idx >> 4, k4 = idx & 15;
      ((float4*)sIn)[r * 16 + k4] = *(const float4*)(src + (size_t)r * stride + k4 * 4);
    }
    __syncthreads();
    for (int kk = 0; kk < 64; kk += 4) {
      float4 w0 = *(const float4*)(sW + (kk + 0) * 128 + cg);
      float4 w1 = *(const float4*)(sW + (kk + 1) * 128 + cg);
      float4 w2 = *(const float4*)(sW + (kk + 2) * 128 + cg);
      float4 w3 = *(const float4*)(sW + (kk + 3) * 128 + cg);
#pragma unroll
      for (int r = 0; r < 8; r++) {
        float4 a = *(const float4*)(sIn + (rg + r) * 64 + kk);
        acc[r][0] = fmaf(a.x, w0.x, acc[r][0]); acc[r][0] = fmaf(a.y, w1.x, acc[r][0]);
        acc[r][0] = fmaf(a.z, w2.x, acc[r][0]); acc[r][0] = fmaf(a.w, w3.x, acc[r][0]);
        acc[r][1] = fmaf(a.x, w0.y, acc[r][1]); acc[r][1] = fmaf(a.y, w1.y, acc[r][1]);
        acc[r][1] = fmaf(a.z, w2.y, acc[r][1]); acc[r][1] = fmaf(a.w, w3.y, acc[r][1]);
        acc[r][2] = fmaf(a.x, w0.z, acc[r][2]); acc[r][2] = fmaf(a.y, w1.z, acc[r][2]);
        acc[r][2] = fmaf(a.z, w2.z, acc[r][2]); acc[r][2] = fmaf(a.w, w3.z, acc[r][2]);
        acc[r][3] = fmaf(a.x, w0.w, acc[r][3]); acc[r][3] = fmaf(a.y, w1.w, acc[r][3]);
        acc[r][3] = fmaf(a.z, w2.w, acc[r][3]); acc[r][3] = fmaf(a.w, w3.w, acc[r][3]);
      }
    }
  }
#pragma unroll
  for (int r = 0; r < 8; r++) {
    float4 o;
    o.x = tanhf(acc[r][0]); o.y = tanhf(acc[r][1]);
    o.z = tanhf(acc[r][2]); o.w = tanhf(acc[r][3]);
    *(float4*)(out + (size_t)(rowbase + rg + r) * 128 + cg) = o;
  }
}

// ---------------------------------------------------------------- launch
extern "C" void kernel_launch(void* const* d_in, const int* in_sizes, int n_in,
                              void* d_out, int out_size, void* d_ws, size_t ws_size,
                              hipStream_t stream) {
  const float* x  = (const float*)d_in[0];
  // d_in[1] = row_splits (int64) — uniform, unused
  const float* Ws = (const float*)d_in[2];
  const float* bs = (const float*)d_in[3];
  const float* Wf = (const float*)d_in[4];
  const float* bf = (const float*)d_in[5];
  const float* W0 = (const float*)d_in[6];
  const float* b0 = (const float*)d_in[7];
  const float* W1 = (const float*)d_in[8];
  const float* b1 = (const float*)d_in[9];
  float* out = (float*)d_out;

  constexpr int N = NPTS;
  float* coords = (float*)d_ws;            // N*4
  float* featA  = coords + (size_t)N * 4;  // N*64
  float* featB  = featA + (size_t)N * 64;  // N*128
  int*   nidxb  = (int*)(featB + (size_t)N * 128);  // N*39
  float* wb     = (float*)(nidxb + (size_t)N * KN); // N*39
  float* aggb   = wb + (size_t)N * KN;               // N*256

  k_transform<<<N / 128, 128, 0, stream>>>(x, Ws, bs, Wf, bf, (float4*)coords, featA);
  k_knn<<<N / 128, 128, 0, stream>>>((const float4*)coords, nidxb, wb);
  k_gather<64><<<(N * 4) / 256, 256, 0, stream>>>(featA, nidxb, wb, aggb);
  k_dense<192><<<N / 64, 256, 0, stream>>>(x, aggb, W0, b0, featB);
  k_gather<128><<<(N * 8) / 256, 256, 0, stream>>>(featB, nidxb, wb, aggb);
  k_dense<320><<<N / 64, 256, 0, stream>>>(x, aggb, W1, b1, out);
}

// Round 2
// 915.935 us; speedup vs baseline: 1.4715x; 1.4715x over previous
//
#include <hip/hip_runtime.h>

// RaggedGravNet_simple on MI355X.
// k_transform: coords+feat GEMMs, also emits packed (-2c) and |c|^2 arrays.
// k_knn: 1 thread/query; wave-uniform scalar scan of the 4096-candidate segment
//        (s = cn_j - 2 q.c_j, rank-equal to d2); branch-free sorted top-40
//        VALUE network in registers; accepted indices appended to an LDS log;
//        final pass re-filters log by exact tau in index order.
// gathers/denses unchanged from round 1.

#define NPTS 32768
#define SEGSZ 4096
#define KN 39
#define LOGCAP 512

// ---------------------------------------------------------------- transform
__global__ __launch_bounds__(128) void k_transform(
    const float* __restrict__ x,
    const float* __restrict__ Ws, const float* __restrict__ bs,
    const float* __restrict__ Wf, const float* __restrict__ bf,
    float4* __restrict__ coords, float4* __restrict__ c2a,
    float* __restrict__ cnv, float* __restrict__ feat) {
  __shared__ float sWf[64 * 64];
  __shared__ float sWs[64 * 4];
  __shared__ float sb[68];
  __shared__ float sx[128 * 65];
  const int t = threadIdx.x;
  for (int i = t; i < 4096; i += 128) sWf[i] = Wf[i];
  for (int i = t; i < 256; i += 128) sWs[i] = Ws[i];
  if (t < 64) sb[t] = bf[t];
  else if (t < 68) sb[t] = bs[t - 64];
  const int rowbase = blockIdx.x * 128;
  for (int i = t; i < 128 * 64; i += 128) {
    int r = i >> 6, k = i & 63;
    sx[r * 65 + k] = x[(size_t)rowbase * 64 + i];
  }
  __syncthreads();
  const float* xr = sx + t * 65;
  float c0 = sb[64], c1 = sb[65], c2 = sb[66], c3 = sb[67];
  for (int k = 0; k < 64; k++) {
    float xs = xr[k];
    c0 = fmaf(xs, sWs[k * 4 + 0], c0);
    c1 = fmaf(xs, sWs[k * 4 + 1], c1);
    c2 = fmaf(xs, sWs[k * 4 + 2], c2);
    c3 = fmaf(xs, sWs[k * 4 + 3], c3);
  }
  const int row = rowbase + t;
  coords[row] = make_float4(c0, c1, c2, c3);
  c2a[row] = make_float4(-2.0f * c0, -2.0f * c1, -2.0f * c2, -2.0f * c3);
  cnv[row] = c0 * c0 + c1 * c1 + c2 * c2 + c3 * c3;
  for (int fc = 0; fc < 64; fc += 16) {
    float acc[16];
#pragma unroll
    for (int j = 0; j < 16; j++) acc[j] = sb[fc + j];
    for (int k = 0; k < 64; k++) {
      float xs = xr[k];
#pragma unroll
      for (int j = 0; j < 16; j++) acc[j] = fmaf(xs, sWf[k * 64 + fc + j], acc[j]);
    }
#pragma unroll
    for (int j = 0; j < 16; j += 4)
      *(float4*)(feat + (size_t)row * 64 + fc + j) =
          make_float4(acc[j], acc[j + 1], acc[j + 2], acc[j + 3]);
  }
}

// ---------------------------------------------------------------- kNN
__global__ __launch_bounds__(64) void k_knn(
    const float4* __restrict__ coords, const float4* __restrict__ c2a,
    const float* __restrict__ cnv, int* __restrict__ nidx,
    float* __restrict__ wout) {
  __shared__ unsigned short jlog[LOGCAP * 64];  // 64 KiB
  const int lane = threadIdx.x;
  const int q = blockIdx.x * 64 + lane;
  const int segbase = q & ~(SEGSZ - 1);
  const int qlocal = q - segbase;
  const float4 qc = coords[q];
  const float cnq = qc.x * qc.x + qc.y * qc.y + qc.z * qc.z + qc.w * qc.w;
  const float4* __restrict__ ca = c2a + segbase;  // wave-uniform base
  const float* __restrict__ cn = cnv + segbase;

  // sorted ascending top-40 VALUES (self included; tau = bd[39])
  float bd[40];
#pragma unroll
  for (int i = 0; i < 40; i++) bd[i] = 1e30f;
  float worst = 1e30f;
  int lp = 0;       // log append count (per lane)
  int drained = 0;  // log prefix already inserted into bd

  // branch-free sorted insert: independent min/max per slot, no divergence.
  auto insert = [&](float s) {
#pragma unroll
    for (int i = 39; i >= 1; i--) bd[i] = fminf(fmaxf(bd[i - 1], s), bd[i]);
    bd[0] = fminf(bd[0], s);
  };

  auto drain = [&]() {
    while (__any(drained < lp)) {
      bool act = drained < lp;
      float s = 1e31f;  // sentinel: insert() is a no-op
      if (act) {
        int j = jlog[drained * 64 + lane];
        float4 a = ca[j];
        s = fmaf(a.x, qc.x, fmaf(a.y, qc.y, fmaf(a.z, qc.z, fmaf(a.w, qc.w, cn[j]))));
        drained++;
      }
      insert(s);
    }
    worst = bd[39];
  };

  auto compact = [&]() {  // drop logged entries that can no longer make top-40
    int myLp = lp, wr = 0;
    for (int rd = 0; __any(rd < myLp); rd++) {
      if (rd < myLp) {
        int j = jlog[rd * 64 + lane];
        float4 a = ca[j];
        float s = fmaf(a.x, qc.x, fmaf(a.y, qc.y, fmaf(a.z, qc.z, fmaf(a.w, qc.w, cn[j]))));
        if (s <= worst) { jlog[wr * 64 + lane] = (unsigned short)j; wr++; }
      }
    }
    lp = wr;
    drained = wr;
  };

#define SCAN_CHUNK(J0, NC)                                                     \
  {                                                                            \
    _Pragma("unroll 16") for (int jj = 0; jj < (NC); jj++) {                   \
      int j = (J0) + jj;                                                       \
      float4 a = ca[j];                                                        \
      float c = cn[j];                                                         \
      float s = fmaf(a.x, qc.x, fmaf(a.y, qc.y, fmaf(a.z, qc.z, fmaf(a.w, qc.w, c)))); \
      if (s <= worst) {                                                        \
        jlog[lp * 64 + lane] = (unsigned short)j;                              \
        lp++;                                                                  \
      }                                                                        \
    }                                                                          \
  }

  SCAN_CHUNK(0, 64); drain();
  SCAN_CHUNK(64, 64); drain();
  SCAN_CHUNK(128, 64); drain();
  SCAN_CHUNK(192, 64); drain();
  for (int base = 256; base < SEGSZ; base += 256) {
    if (__any(lp >= LOGCAP - 256)) compact();
    SCAN_CHUNK(base, 256);
    drain();
  }
#undef SCAN_CHUNK

  // final: emit first 39 (by index order) with s <= tau, excluding self.
  const float tau = bd[39];
  int cnt = 0;
  for (int rd = 0; __any(rd < lp && cnt < KN); rd++) {
    if (rd < lp && cnt < KN) {
      int j = jlog[rd * 64 + lane];
      float4 a = ca[j];
      float s = fmaf(a.x, qc.x, fmaf(a.y, qc.y, fmaf(a.z, qc.z, fmaf(a.w, qc.w, cn[j]))));
      if (s <= tau && j != qlocal) {
        nidx[(size_t)q * KN + cnt] = segbase + j;
        float d2 = s + cnq;
        wout[(size_t)q * KN + cnt] = expf(-(d2 * 10.0f + 1e-5f));
        cnt++;
      }
    }
  }
}

// ---------------------------------------------------------------- gather/agg
template <int F>
__global__ __launch_bounds__(256) void k_gather(
    const float* __restrict__ feat, const int* __restrict__ nidx,
    const float* __restrict__ w, float* __restrict__ agg) {
  constexpr int TPR = F / 16;
  const int gid = blockIdx.x * 256 + threadIdx.x;
  const int row = gid / TPR;
  const int fb = (gid % TPR) * 16;
  float mx[16], sm[16];
#pragma unroll
  for (int j = 0; j < 16; j++) { mx[j] = -1e30f; sm[j] = 0.0f; }
  const int* ni = nidx + (size_t)row * KN;
  const float* wr = w + (size_t)row * KN;
  for (int k = 0; k < KN; k++) {
    int n = ni[k];
    float wv = wr[k];
    const float4* fp = (const float4*)(feat + (size_t)n * F + fb);
#pragma unroll
    for (int v = 0; v < 4; v++) {
      float4 f4 = fp[v];
      float a;
      a = f4.x * wv; mx[4 * v + 0] = fmaxf(mx[4 * v + 0], a); sm[4 * v + 0] += a;
      a = f4.y * wv; mx[4 * v + 1] = fmaxf(mx[4 * v + 1], a); sm[4 * v + 1] += a;
      a = f4.z * wv; mx[4 * v + 2] = fmaxf(mx[4 * v + 2], a); sm[4 * v + 2] += a;
      a = f4.w * wv; mx[4 * v + 3] = fmaxf(mx[4 * v + 3], a); sm[4 * v + 3] += a;
    }
  }
  const float inv = 1.0f / (float)KN;
  float* am = agg + (size_t)row * (2 * F) + fb;
#pragma unroll
  for (int v = 0; v < 4; v++)
    ((float4*)am)[v] = make_float4(mx[4 * v], mx[4 * v + 1], mx[4 * v + 2], mx[4 * v + 3]);
  float* as = am + F;
#pragma unroll
  for (int v = 0; v < 4; v++)
    ((float4*)as)[v] = make_float4(sm[4 * v] * inv, sm[4 * v + 1] * inv,
                                   sm[4 * v + 2] * inv, sm[4 * v + 3] * inv);
}

// ---------------------------------------------------------------- dense+tanh
template <int KDIM>
__global__ __launch_bounds__(256) void k_dense(
    const float* __restrict__ x, const float* __restrict__ agg,
    const float* __restrict__ W, const float* __restrict__ b,
    float* __restrict__ out) {
  __shared__ __align__(16) float sW[64 * 128];
  __shared__ __align__(16) float sIn[64 * 64];
  const int t = threadIdx.x;
  const int rowbase = blockIdx.x * 64;
  const int cg = (t & 31) * 4;
  const int rg = (t >> 5) * 8;
  constexpr int ASTRIDE = KDIM - 64;
  float acc[8][4];
  float4 bv = *(const float4*)(b + cg);
#pragma unroll
  for (int r = 0; r < 8; r++) {
    acc[r][0] = bv.x; acc[r][1] = bv.y; acc[r][2] = bv.z; acc[r][3] = bv.w;
  }
  for (int kt = 0; kt < KDIM; kt += 64) {
    __syncthreads();
#pragma unroll
    for (int i = 0; i < 8; i++) {
      int idx = t + i * 256;
      ((float4*)sW)[idx] = ((const float4*)(W + (size_t)kt * 128))[idx];
    }
    const float* src = (kt == 0) ? (x + (size_t)rowbase * 64)
                                 : (agg + (size_t)rowbase * ASTRIDE + (kt - 64));
    const int stride = (kt == 0) ? 64 : ASTRIDE;
#pragma unroll
    for (int i = 0; i < 4; i++) {
      int idx = t + i * 256;
      int r = idx >> 4, k4 = idx & 15;
      ((float4*)sIn)[r * 16 + k4] = *(const float4*)(src + (size_t)r * stride + k4 * 4);
    }
    __syncthreads();
    for (int kk = 0; kk < 64; kk += 4) {
      float4 w0 = *(const float4*)(sW + (kk + 0) * 128 + cg);
      float4 w1 = *(const float4*)(sW + (kk + 1) * 128 + cg);
      float4 w2 = *(const float4*)(sW + (kk + 2) * 128 + cg);
      float4 w3 = *(const float4*)(sW + (kk + 3) * 128 + cg);
#pragma unroll
      for (int r = 0; r < 8; r++) {
        float4 a = *(const float4*)(sIn + (rg + r) * 64 + kk);
        acc[r][0] = fmaf(a.x, w0.x, acc[r][0]); acc[r][0] = fmaf(a.y, w1.x, acc[r][0]);
        acc[r][0] = fmaf(a.z, w2.x, acc[r][0]); acc[r][0] = fmaf(a.w, w3.x, acc[r][0]);
        acc[r][1] = fmaf(a.x, w0.y, acc[r][1]); acc[r][1] = fmaf(a.y, w1.y, acc[r][1]);
        acc[r][1] = fmaf(a.z, w2.y, acc[r][1]); acc[r][1] = fmaf(a.w, w3.y, acc[r][1]);
        acc[r][2] = fmaf(a.x, w0.z, acc[r][2]); acc[r][2] = fmaf(a.y, w1.z, acc[r][2]);
        acc[r][2] = fmaf(a.z, w2.z, acc[r][2]); acc[r][2] = fmaf(a.w, w3.z, acc[r][2]);
        acc[r][3] = fmaf(a.x, w0.w, acc[r][3]); acc[r][3] = fmaf(a.y, w1.w, acc[r][3]);
        acc[r][3] = fmaf(a.z, w2.w, acc[r][3]); acc[r][3] = fmaf(a.w, w3.w, acc[r][3]);
      }
    }
  }
#pragma unroll
  for (int r = 0; r < 8; r++) {
    float4 o;
    o.x = tanhf(acc[r][0]); o.y = tanhf(acc[r][1]);
    o.z = tanhf(acc[r][2]); o.w = tanhf(acc[r][3]);
    *(float4*)(out + (size_t)(rowbase + rg + r) * 128 + cg) = o;
  }
}

// ---------------------------------------------------------------- launch
extern "C" void kernel_launch(void* const* d_in, const int* in_sizes, int n_in,
                              void* d_out, int out_size, void* d_ws, size_t ws_size,
                              hipStream_t stream) {
  const float* x  = (const float*)d_in[0];
  // d_in[1] = row_splits (int64) — uniform, unused
  const float* Ws = (const float*)d_in[2];
  const float* bs = (const float*)d_in[3];
  const float* Wf = (const float*)d_in[4];
  const float* bf = (const float*)d_in[5];
  const float* W0 = (const float*)d_in[6];
  const float* b0 = (const float*)d_in[7];
  const float* W1 = (const float*)d_in[8];
  const float* b1 = (const float*)d_in[9];
  float* out = (float*)d_out;

  constexpr int N = NPTS;
  float* coords = (float*)d_ws;                       // N*4
  float* c2a    = coords + (size_t)N * 4;             // N*4
  float* cnvb   = c2a + (size_t)N * 4;                // N
  float* featA  = cnvb + (size_t)N;                   // N*64
  float* featB  = featA + (size_t)N * 64;             // N*128
  int*   nidxb  = (int*)(featB + (size_t)N * 128);    // N*39
  float* wb     = (float*)(nidxb + (size_t)N * KN);   // N*39
  float* aggb   = wb + (size_t)N * KN;                // N*256

  k_transform<<<N / 128, 128, 0, stream>>>(x, Ws, bs, Wf, bf,
                                           (float4*)coords, (float4*)c2a, cnvb, featA);
  k_knn<<<N / 64, 64, 0, stream>>>((const float4*)coords, (const float4*)c2a,
                                   cnvb, nidxb, wb);
  k_gather<64><<<(N * 4) / 256, 256, 0, stream>>>(featA, nidxb, wb, aggb);
  k_dense<192><<<N / 64, 256, 0, stream>>>(x, aggb, W0, b0, featB);
  k_gather<128><<<(N * 8) / 256, 256, 0, stream>>>(featB, nidxb, wb, aggb);
  k_dense<320><<<N / 64, 256, 0, stream>>>(x, aggb, W1, b1, out);
}